// Round 1
// baseline (204.061 us; speedup 1.0000x reference)
//
#include <hip/hip_runtime.h>

#define NQ     14
#define DIMQ   16384     // 2^14
#define NPAIR  13
#define NTROT  10

// LDS index swizzle: XOR low 4 bits with bits 4-7. Makes every gate-pass
// access pattern (strides 2^0, 2^4, 2^8, 2^12) land at the 4-way b64 bank
// floor instead of 64-way serialization on the stride-1 group.
__device__ __forceinline__ int swz(int k) { return k ^ ((k >> 4) & 15); }

__device__ __forceinline__ float2 cmulf(float2 a, float2 b) {
    return make_float2(a.x * b.x - a.y * b.y, a.x * b.y + a.y * b.x);
}

struct Smem {
    float2 psi[DIMQ];    // 128 KiB statevector
    float2 tabLo[64];    // e^{i phi} for ZZ couplers 0..5
    float2 tabHi[128];   // e^{i phi} for ZZ couplers 6..12
    float  red[48];      // block reduction of the 42 constants
};

// Apply RX gates on qubits [Q0, Q0+M) (optionally fusing the ZZ diagonal
// first). Each thread stages one coset of 2^M amplitudes in registers.
template <int Q0, int M, bool FUSE_ZZ>
__device__ __forceinline__ void rx_pass(Smem& sm, const float* cg, const float* sg, int t) {
    constexpr int NA   = 1 << M;
    constexpr int NC   = DIMQ >> M;
    constexpr int LOWM = (1 << Q0) - 1;
    for (int c = t; c < NC; c += 1024) {
        const int low  = c & LOWM;
        const int high = c >> Q0;
        const int base = (high << (Q0 + M)) | low;
        float2 r[NA];
#pragma unroll
        for (int j = 0; j < NA; ++j) r[j] = sm.psi[swz(base + (j << Q0))];
        if constexpr (FUSE_ZZ) {
#pragma unroll
            for (int j = 0; j < NA; ++j) {
                const int k = base + (j << Q0);
                const int d = k ^ (k >> 1);   // coupler-disagreement bits
                const float2 rot = cmulf(sm.tabLo[d & 63], sm.tabHi[(d >> 6) & 127]);
                r[j] = cmulf(r[j], rot);
            }
        }
#pragma unroll
        for (int l = 0; l < M; ++l) {
            const float cc = cg[Q0 + l];
            const float ss = sg[Q0 + l];
#pragma unroll
            for (int jj = 0; jj < NA / 2; ++jj) {
                const int j0 = ((jj >> l) << (l + 1)) | (jj & ((1 << l) - 1));
                const int j1 = j0 | (1 << l);
                const float2 p0 = r[j0];
                const float2 p1 = r[j1];
                // RX: new0 = c*p0 - i s * p1 ; new1 = -i s * p0 + c*p1
                r[j0] = make_float2(cc * p0.x + ss * p1.y, cc * p0.y - ss * p1.x);
                r[j1] = make_float2(cc * p1.x + ss * p0.y, cc * p1.y - ss * p0.x);
            }
        }
#pragma unroll
        for (int j = 0; j < NA; ++j) sm.psi[swz(base + (j << Q0))] = r[j];
    }
    __syncthreads();
}

extern "C" __global__ void __launch_bounds__(1024)
qr_evolve(const float* __restrict__ J, const float* __restrict__ g,
          float* __restrict__ consts /* 42 floats in d_ws */) {
    __shared__ Smem sm;
    const int t  = threadIdx.x;
    const float dt = 0.1f;   // EVO_TIME / N_TROTTER

    // H^{\otimes 14}|0> = uniform +2^-7 (exact in fp32)
    const float amp = 0.0078125f;
    for (int k = t; k < DIMQ; k += 1024) sm.psi[k] = make_float2(amp, 0.0f);
    if (t < 48) sm.red[t] = 0.0f;

    // ZZ phase tables: element k picks up exp(i*phi), phi = sum_i h_i * (+1 if
    // bits i,i+1 differ else -1), h_i = 0.5*J[i]*dt
    if (t < 64) {
        float phi = 0.0f;
        for (int i = 0; i < 6; ++i) {
            const float h = 0.5f * J[i] * dt;
            phi += ((t >> i) & 1) ? h : -h;
        }
        float s, c; __sincosf(phi, &s, &c);
        sm.tabLo[t] = make_float2(c, s);
    } else if (t < 192) {
        const int v = t - 64;
        float phi = 0.0f;
        for (int i = 0; i < 7; ++i) {
            const float h = 0.5f * J[6 + i] * dt;
            phi += ((v >> i) & 1) ? h : -h;
        }
        float s, c; __sincosf(phi, &s, &c);
        sm.tabHi[v] = make_float2(c, s);
    }

    // RX gate parameters (uniform across threads)
    float cg[NQ], sg[NQ];
#pragma unroll
    for (int i = 0; i < NQ; ++i) {
        const float h = 0.5f * g[i] * dt;
        __sincosf(h, &sg[i], &cg[i]);
    }
    __syncthreads();

    for (int step = 0; step < NTROT; ++step) {
        rx_pass<0, 4, true >(sm, cg, sg, t);   // ZZ diag + RX q0..3
        rx_pass<4, 4, false>(sm, cg, sg, t);   // RX q4..7
        rx_pass<8, 4, false>(sm, cg, sg, t);   // RX q8..11
        rx_pass<12, 2, false>(sm, cg, sg, t);  // RX q12..13
    }

    // Per-qubit constants. Output triple i uses bit q = 13-i:
    //   C_i = sum_{k0: bit_q=0} conj(psi[k0]) * psi[k0 + 2^q]
    //   Z_i = sum_k s_q(k) |psi[k]|^2
    const int lane = t & 63;
#pragma unroll 1
    for (int i = 0; i < NQ; ++i) {
        const int q = 13 - i;
        float cr = 0.0f, ci = 0.0f, z = 0.0f;
        for (int p = t; p < DIMQ / 2; p += 1024) {
            const int k0 = ((p >> q) << (q + 1)) | (p & ((1 << q) - 1));
            const int k1 = k0 | (1 << q);
            const float2 a = sm.psi[swz(k0)];
            const float2 b = sm.psi[swz(k1)];
            cr += a.x * b.x + a.y * b.y;   // Re(conj(a)*b)
            ci += a.x * b.y - a.y * b.x;   // Im(conj(a)*b)
            z  += (a.x * a.x + a.y * a.y) - (b.x * b.x + b.y * b.y);
        }
#pragma unroll
        for (int off = 32; off > 0; off >>= 1) {
            cr += __shfl_down(cr, off);
            ci += __shfl_down(ci, off);
            z  += __shfl_down(z, off);
        }
        if (lane == 0) {
            atomicAdd(&sm.red[3 * i + 0], cr);
            atomicAdd(&sm.red[3 * i + 1], ci);
            atomicAdd(&sm.red[3 * i + 2], z);
        }
    }
    __syncthreads();
    if (t < 42) consts[t] = sm.red[t];
}

extern "C" __global__ void __launch_bounds__(256)
qr_expect(const float* __restrict__ x, const float* __restrict__ consts,
          float* __restrict__ out, int batch) {
    const int tid = blockIdx.x * blockDim.x + threadIdx.x;
    if (tid >= batch * NQ) return;
    const int b = tid / NQ;
    const int i = tid - b * NQ;
    const int q = 13 - i;    // output triple i measures qubit bit 13-i
    const float xv = x[b * NQ + q];
    const float cr = consts[3 * i + 0];
    const float ci = consts[3 * i + 1];
    const float zz = consts[3 * i + 2];
    float s, c;
    __sincosf(xv, &s, &c);
    float* o = out + b * (3 * NQ) + 3 * i;
    o[0] = 2.0f * (c * cr - s * ci);   // 2*Re(e^{ix} C)
    o[1] = 2.0f * (s * cr + c * ci);   // 2*Im(e^{ix} C)
    o[2] = zz;
}

extern "C" void kernel_launch(void* const* d_in, const int* in_sizes, int n_in,
                              void* d_out, int out_size, void* d_ws, size_t ws_size,
                              hipStream_t stream) {
    const float* x = (const float*)d_in[0];
    const float* J = (const float*)d_in[1];
    const float* g = (const float*)d_in[2];
    float* out    = (float*)d_out;
    float* consts = (float*)d_ws;   // 42 floats of scratch
    const int batch = in_sizes[0] / NQ;

    hipLaunchKernelGGL(qr_evolve, dim3(1), dim3(1024), 0, stream, J, g, consts);

    const int threads = batch * NQ;
    const int blocks  = (threads + 255) / 256;
    hipLaunchKernelGGL(qr_expect, dim3(blocks), dim3(256), 0, stream, x, consts, out, batch);
}

// Round 2
// 171.662 us; speedup vs baseline: 1.1887x; 1.1887x over previous
//
#include <hip/hip_runtime.h>
#include <hip/hip_cooperative_groups.h>

namespace cg = cooperative_groups;

#define NQ     14
#define DIMQ   16384
#define NTROT  10
#define NWG    16
#define NTHR   256

struct Smem {
    float2 slab[1024];   // 8 KiB per-WG staging slab (one coset)
    float2 tabLo[64];    // e^{i phi} for ZZ couplers 0..5
    float2 tabHi[128];   // e^{i phi} for ZZ couplers 6..12
    float  red[3];
};

__device__ __forceinline__ float2 cmulf(float2 a, float2 b) {
    return make_float2(a.x * b.x - a.y * b.y, a.x * b.y + a.y * b.x);
}

// RX butterfly on an in-thread pair: p0' = c p0 - i s p1 ; p1' = c p1 - i s p0
__device__ __forceinline__ void bfly(float2& p0, float2& p1, float c, float s) {
    float2 n0 = make_float2(c * p0.x + s * p1.y, c * p0.y - s * p1.x);
    float2 n1 = make_float2(c * p1.x + s * p0.y, c * p1.y - s * p0.x);
    p0 = n0; p1 = n1;
}

// RX butterfly via lane exchange (partner = lane ^ mask). The update is
// symmetric in the pair: r' = c*r - i*s*partner, same formula on both lanes.
__device__ __forceinline__ void bfly_shfl(float2& p, int mask, float c, float s) {
    float qx = __shfl_xor(p.x, mask);
    float qy = __shfl_xor(p.y, mask);
    p = make_float2(c * p.x + s * qy, c * p.y - s * qx);
}

// ZZ diagonal: element k picks up exp(i*phi(k)), phi from 13 coupler bits of
// d = k ^ (k>>1), split across two LDS tables.
__device__ __forceinline__ void zz_apply(const Smem& sm, float2& a, int k) {
    int d = (k ^ (k >> 1)) & 0x1FFF;
    float2 rot = cmulf(sm.tabLo[d & 63], sm.tabHi[d >> 6]);
    a = cmulf(a, rot);
}

// Residency mapping1: thread t holds slab indices m = (t<<2)|j  (reg = slab bits 0,1)
// Residency mapping2: thread t holds slab indices m = t|(j<<8)  (reg = slab bits 8,9)
__device__ __forceinline__ void stage_12(float2* slab, float2 r[4], int t) {
    __syncthreads();
#pragma unroll
    for (int j = 0; j < 4; ++j) slab[(t << 2) | j] = r[j];
    __syncthreads();
#pragma unroll
    for (int j = 0; j < 4; ++j) r[j] = slab[t | (j << 8)];
}
__device__ __forceinline__ void stage_21(float2* slab, float2 r[4], int t) {
    __syncthreads();
#pragma unroll
    for (int j = 0; j < 4; ++j) slab[t | (j << 8)] = r[j];
    __syncthreads();
#pragma unroll
    for (int j = 0; j < 4; ++j) r[j] = slab[(t << 2) | j];
}

// Layout A: slab bit b == qubit b; WG w = qubits 10..13; k = (w<<10)|m.
// FIRST: init uniform state instead of loading. NEXT: apply ZZ + RX{0..9}.
// !FIRST: first apply previous step's leftover RX{0..3}.
template <bool FIRST, bool NEXT>
__device__ void phaseA(Smem& sm, float2* psi, int w, int t,
                       const float* c, const float* s) {
    float2 r[4];
    if (FIRST) {
#pragma unroll
        for (int j = 0; j < 4; ++j) r[j] = make_float2(0.0078125f, 0.0f);
    } else {
#pragma unroll
        for (int j = 0; j < 4; ++j) r[j] = psi[(w << 10) | (t << 2) | j];
    }
    if (!FIRST) {  // RX_s on qubits 0..3: reg0, reg1, lane masks 1,2
        bfly(r[0], r[1], c[0], s[0]); bfly(r[2], r[3], c[0], s[0]);
        bfly(r[0], r[2], c[1], s[1]); bfly(r[1], r[3], c[1], s[1]);
#pragma unroll
        for (int j = 0; j < 4; ++j) bfly_shfl(r[j], 1, c[2], s[2]);
#pragma unroll
        for (int j = 0; j < 4; ++j) bfly_shfl(r[j], 2, c[3], s[3]);
    }
    if (NEXT) {
#pragma unroll
        for (int j = 0; j < 4; ++j) zz_apply(sm, r[j], (w << 10) | (t << 2) | j);
        // RX_{s+1} qubits 0..7 in mapping1
        bfly(r[0], r[1], c[0], s[0]); bfly(r[2], r[3], c[0], s[0]);
        bfly(r[0], r[2], c[1], s[1]); bfly(r[1], r[3], c[1], s[1]);
#pragma unroll
        for (int b = 0; b < 6; ++b) {
#pragma unroll
            for (int j = 0; j < 4; ++j) bfly_shfl(r[j], 1 << b, c[2 + b], s[2 + b]);
        }
        stage_12(sm.slab, r, t);   // reg bits now = qubits 8,9
        bfly(r[0], r[1], c[8], s[8]); bfly(r[2], r[3], c[8], s[8]);
        bfly(r[0], r[2], c[9], s[9]); bfly(r[1], r[3], c[9], s[9]);
#pragma unroll
        for (int j = 0; j < 4; ++j) psi[(w << 10) | t | (j << 8)] = r[j];
    } else {
#pragma unroll
        for (int j = 0; j < 4; ++j) psi[(w << 10) | (t << 2) | j] = r[j];
    }
}

// Layout B: slab bit b == qubit b+4; WG w = qubits 0..3; k = (m<<4)|w.
// Does RX_s{10..13}, ZZ_{s+1}, RX_{s+1}{4..13}.
__device__ void phaseB(Smem& sm, float2* psi, int w, int t,
                       const float* c, const float* s) {
    float2 r[4];
#pragma unroll
    for (int j = 0; j < 4; ++j) r[j] = psi[((((t << 2) | j)) << 4) | w];
    // RX_s qubits 10,11 = slab 6,7 = lane bits 4,5
#pragma unroll
    for (int j = 0; j < 4; ++j) bfly_shfl(r[j], 16, c[10], s[10]);
#pragma unroll
    for (int j = 0; j < 4; ++j) bfly_shfl(r[j], 32, c[11], s[11]);
    stage_12(sm.slab, r, t);       // reg bits now = slab 8,9 = qubits 12,13
    bfly(r[0], r[1], c[12], s[12]); bfly(r[2], r[3], c[12], s[12]);
    bfly(r[0], r[2], c[13], s[13]); bfly(r[1], r[3], c[13], s[13]);
    // ZZ_{s+1} (diagonal, mapping-agnostic)
#pragma unroll
    for (int j = 0; j < 4; ++j) zz_apply(sm, r[j], ((t | (j << 8)) << 4) | w);
    // RX_{s+1} qubits 12,13 (reg) then 4..9 (lane masks 1..32)
    bfly(r[0], r[1], c[12], s[12]); bfly(r[2], r[3], c[12], s[12]);
    bfly(r[0], r[2], c[13], s[13]); bfly(r[1], r[3], c[13], s[13]);
#pragma unroll
    for (int b = 0; b < 6; ++b) {
#pragma unroll
        for (int j = 0; j < 4; ++j) bfly_shfl(r[j], 1 << b, c[4 + b], s[4 + b]);
    }
    stage_21(sm.slab, r, t);       // back to mapping1
    // RX_{s+1} qubits 10,11 = lane bits 4,5
#pragma unroll
    for (int j = 0; j < 4; ++j) bfly_shfl(r[j], 16, c[10], s[10]);
#pragma unroll
    for (int j = 0; j < 4; ++j) bfly_shfl(r[j], 32, c[11], s[11]);
#pragma unroll
    for (int j = 0; j < 4; ++j) psi[((((t << 2) | j)) << 4) | w] = r[j];
}

extern "C" __global__ void __launch_bounds__(NTHR)
qr_all(const float* __restrict__ x, const float* __restrict__ J,
       const float* __restrict__ g, float* __restrict__ out,
       float2* __restrict__ psi, float* __restrict__ consts) {
    cg::grid_group grid = cg::this_grid();
    __shared__ Smem sm;
    const int w = blockIdx.x;
    const int t = threadIdx.x;
    const float dt = 0.1f;   // EVO_TIME / N_TROTTER

    // ZZ phase tables (per WG). phi = sum_i 0.5*J_i*dt * (bit differ ? +1 : -1)
    if (t < 64) {
        float phi = 0.0f;
        for (int i = 0; i < 6; ++i) {
            const float h = 0.5f * J[i] * dt;
            phi += ((t >> i) & 1) ? h : -h;
        }
        float sn, cs; __sincosf(phi, &sn, &cs);
        sm.tabLo[t] = make_float2(cs, sn);
    } else if (t < 192) {
        const int v = t - 64;
        float phi = 0.0f;
        for (int i = 0; i < 7; ++i) {
            const float h = 0.5f * J[6 + i] * dt;
            phi += ((v >> i) & 1) ? h : -h;
        }
        float sn, cs; __sincosf(phi, &sn, &cs);
        sm.tabHi[v] = make_float2(cs, sn);
    }
    float cc[NQ], ss[NQ];
#pragma unroll
    for (int i = 0; i < NQ; ++i) __sincosf(0.5f * g[i] * dt, &ss[i], &cc[i]);
    __syncthreads();

    // Phase 1 (A): ZZ_1 + RX_1{0..9}
    phaseA<true, true>(sm, psi, w, t, cc, ss);
    __threadfence(); grid.sync();

    // Phases 2..10: finish step s, start step s+1
    for (int sstep = 1; sstep <= 9; ++sstep) {
        if (sstep & 1) phaseB(sm, psi, w, t, cc, ss);
        else           phaseA<false, true>(sm, psi, w, t, cc, ss);
        __threadfence(); grid.sync();
    }

    // Phase 11 (A): RX_10{0..3} only
    phaseA<false, false>(sm, psi, w, t, cc, ss);
    __threadfence(); grid.sync();

    // Phase 12: reductions — WG i computes triple i (qubit q = 13-i)
    if (w < NQ) {
        const int q = 13 - w;
        float cr = 0.0f, ci = 0.0f, z = 0.0f;
        for (int p = t; p < DIMQ / 2; p += NTHR) {
            const int k0 = ((p >> q) << (q + 1)) | (p & ((1 << q) - 1));
            const float2 a = psi[k0];
            const float2 b = psi[k0 | (1 << q)];
            cr += a.x * b.x + a.y * b.y;
            ci += a.x * b.y - a.y * b.x;
            z  += (a.x * a.x + a.y * a.y) - (b.x * b.x + b.y * b.y);
        }
#pragma unroll
        for (int off = 32; off > 0; off >>= 1) {
            cr += __shfl_down(cr, off);
            ci += __shfl_down(ci, off);
            z  += __shfl_down(z, off);
        }
        if (t == 0) { sm.red[0] = 0.0f; sm.red[1] = 0.0f; sm.red[2] = 0.0f; }
        __syncthreads();
        if ((t & 63) == 0) {
            atomicAdd(&sm.red[0], cr);
            atomicAdd(&sm.red[1], ci);
            atomicAdd(&sm.red[2], z);
        }
        __syncthreads();
        if (t == 0) {
            consts[3 * w + 0] = sm.red[0];
            consts[3 * w + 1] = sm.red[1];
            consts[3 * w + 2] = sm.red[2];
        }
    }
    __threadfence(); grid.sync();

    // Phase 13: batched expectations (fused epilogue)
    const int gtid = w * NTHR + t;
    for (int task = gtid; task < 2048 * NQ; task += NWG * NTHR) {
        const int b = task / NQ;
        const int i = task - b * NQ;
        const int q = 13 - i;
        const float xv = x[b * NQ + q];
        const float cr = consts[3 * i + 0];
        const float ci = consts[3 * i + 1];
        const float zz = consts[3 * i + 2];
        float sn, cs; __sincosf(xv, &sn, &cs);
        float* o = out + b * (3 * NQ) + 3 * i;
        o[0] = 2.0f * (cs * cr - sn * ci);
        o[1] = 2.0f * (sn * cr + cs * ci);
        o[2] = zz;
    }
}

extern "C" void kernel_launch(void* const* d_in, const int* in_sizes, int n_in,
                              void* d_out, int out_size, void* d_ws, size_t ws_size,
                              hipStream_t stream) {
    const float* x = (const float*)d_in[0];
    const float* J = (const float*)d_in[1];
    const float* g = (const float*)d_in[2];
    float* out    = (float*)d_out;
    float2* psi   = (float2*)d_ws;                                 // 128 KiB
    float* consts = (float*)((char*)d_ws + DIMQ * sizeof(float2)); // 42 floats
    (void)in_sizes; (void)n_in; (void)out_size; (void)ws_size;

    void* args[] = {(void*)&x, (void*)&J, (void*)&g, (void*)&out,
                    (void*)&psi, (void*)&consts};
    hipLaunchCooperativeKernel(reinterpret_cast<void*>(qr_all),
                               dim3(NWG), dim3(NTHR), args, 0, stream);
}

// Round 3
// 111.046 us; speedup vs baseline: 1.8376x; 1.5459x over previous
//
#include <hip/hip_runtime.h>

#define NQ     14
#define DIMQ   16384
#define NTROT  10
#define NWG    16
#define NTHR   256

struct Smem {
    float2 slab[1024];   // 8 KiB per-WG staging slab (one coset)
    float2 tabLo[64];    // e^{i phi} for ZZ couplers 0..5
    float2 tabHi[128];   // e^{i phi} for ZZ couplers 6..12
    float  red[48];      // per-WG partial sums of the 42 constants
};

// ---------- device-coherent (cross-XCD) accessors: sc0 sc1, bypass L1/L2 ----
__device__ __forceinline__ float2 cload2(const float2* p) {
    union { unsigned long long u; float2 f; } x;
    x.u = __hip_atomic_load((const unsigned long long*)p,
                            __ATOMIC_RELAXED, __HIP_MEMORY_SCOPE_AGENT);
    return x.f;
}
__device__ __forceinline__ void cstore2(float2* p, float2 v) {
    union { unsigned long long u; float2 f; } x;
    x.f = v;
    __hip_atomic_store((unsigned long long*)p, x.u,
                       __ATOMIC_RELAXED, __HIP_MEMORY_SCOPE_AGENT);
}
__device__ __forceinline__ float cloadf(const float* p) {
    return __hip_atomic_load(p, __ATOMIC_RELAXED, __HIP_MEMORY_SCOPE_AGENT);
}

// Monotone-counter spin barrier. All shared data moves via sc0/sc1 coherent
// accesses (never dirties L2), so no release fence / L2 writeback is needed:
// __syncthreads() already drains each wave's vmcnt before thread 0 arrives.
__device__ __forceinline__ void gbar(int* cnt, int target) {
    __syncthreads();
    if (threadIdx.x == 0) {
        __hip_atomic_fetch_add(cnt, 1, __ATOMIC_RELAXED, __HIP_MEMORY_SCOPE_AGENT);
        while (__hip_atomic_load(cnt, __ATOMIC_RELAXED, __HIP_MEMORY_SCOPE_AGENT) < target)
            __builtin_amdgcn_s_sleep(2);
    }
    __syncthreads();
}

// ---------------------------------------------------------------------------
__device__ __forceinline__ float2 cmulf(float2 a, float2 b) {
    return make_float2(a.x * b.x - a.y * b.y, a.x * b.y + a.y * b.x);
}
__device__ __forceinline__ void bfly(float2& p0, float2& p1, float c, float s) {
    float2 n0 = make_float2(c * p0.x + s * p1.y, c * p0.y - s * p1.x);
    float2 n1 = make_float2(c * p1.x + s * p0.y, c * p1.y - s * p0.x);
    p0 = n0; p1 = n1;
}
__device__ __forceinline__ void bfly_shfl(float2& p, int mask, float c, float s) {
    float qx = __shfl_xor(p.x, mask);
    float qy = __shfl_xor(p.y, mask);
    p = make_float2(c * p.x + s * qy, c * p.y - s * qx);
}
__device__ __forceinline__ void zz_apply(const Smem& sm, float2& a, int k) {
    int d = (k ^ (k >> 1)) & 0x1FFF;
    float2 rot = cmulf(sm.tabLo[d & 63], sm.tabHi[d >> 6]);
    a = cmulf(a, rot);
}
__device__ __forceinline__ void stage_12(float2* slab, float2 r[4], int t) {
    __syncthreads();
#pragma unroll
    for (int j = 0; j < 4; ++j) slab[(t << 2) | j] = r[j];
    __syncthreads();
#pragma unroll
    for (int j = 0; j < 4; ++j) r[j] = slab[t | (j << 8)];
}
__device__ __forceinline__ void stage_21(float2* slab, float2 r[4], int t) {
    __syncthreads();
#pragma unroll
    for (int j = 0; j < 4; ++j) slab[t | (j << 8)] = r[j];
    __syncthreads();
#pragma unroll
    for (int j = 0; j < 4; ++j) r[j] = slab[(t << 2) | j];
}

// Reduce expectation triple i over the WG's slab; qubit sits at slab bit sb.
__device__ __forceinline__ void reduce_qubit(Smem& sm, int sb, int i, int t) {
    float cr = 0.f, ci = 0.f, z = 0.f;
#pragma unroll
    for (int j = 0; j < 4; ++j) {
        const int m = (t << 2) | j;
        const float2 a = sm.slab[m];
        const float n = a.x * a.x + a.y * a.y;
        if ((m >> sb) & 1) {
            z -= n;
        } else {
            z += n;
            const float2 b = sm.slab[m ^ (1 << sb)];
            cr += a.x * b.x + a.y * b.y;
            ci += a.x * b.y - a.y * b.x;
        }
    }
#pragma unroll
    for (int off = 32; off; off >>= 1) {
        cr += __shfl_down(cr, off);
        ci += __shfl_down(ci, off);
        z  += __shfl_down(z, off);
    }
    if ((t & 63) == 0) {
        atomicAdd(&sm.red[3 * i + 0], cr);
        atomicAdd(&sm.red[3 * i + 1], ci);
        atomicAdd(&sm.red[3 * i + 2], z);
    }
}

// Layout A: k = (w<<10)|m, slab bit b == qubit b (WG w = qubits 10..13).
template <bool FIRST>
__device__ void phaseA(Smem& sm, float2* psi, int w, int t,
                       const float* c, const float* s) {
    float2 r[4];
    if (FIRST) {
#pragma unroll
        for (int j = 0; j < 4; ++j) r[j] = make_float2(0.0078125f, 0.0f);
    } else {
#pragma unroll
        for (int j = 0; j < 4; ++j) r[j] = cload2(&psi[(w << 10) | (t << 2) | j]);
        // leftover RX_s{0..3}
        bfly(r[0], r[1], c[0], s[0]); bfly(r[2], r[3], c[0], s[0]);
        bfly(r[0], r[2], c[1], s[1]); bfly(r[1], r[3], c[1], s[1]);
#pragma unroll
        for (int j = 0; j < 4; ++j) bfly_shfl(r[j], 1, c[2], s[2]);
#pragma unroll
        for (int j = 0; j < 4; ++j) bfly_shfl(r[j], 2, c[3], s[3]);
    }
    // ZZ_{s+1} + RX_{s+1}{0..9}
#pragma unroll
    for (int j = 0; j < 4; ++j) zz_apply(sm, r[j], (w << 10) | (t << 2) | j);
    bfly(r[0], r[1], c[0], s[0]); bfly(r[2], r[3], c[0], s[0]);
    bfly(r[0], r[2], c[1], s[1]); bfly(r[1], r[3], c[1], s[1]);
#pragma unroll
    for (int b = 0; b < 6; ++b) {
#pragma unroll
        for (int j = 0; j < 4; ++j) bfly_shfl(r[j], 1 << b, c[2 + b], s[2 + b]);
    }
    stage_12(sm.slab, r, t);   // reg bits now = qubits 8,9
    bfly(r[0], r[1], c[8], s[8]); bfly(r[2], r[3], c[8], s[8]);
    bfly(r[0], r[2], c[9], s[9]); bfly(r[1], r[3], c[9], s[9]);
#pragma unroll
    for (int j = 0; j < 4; ++j) cstore2(&psi[(w << 10) | t | (j << 8)], r[j]);
}

// Layout B: k = (m<<4)|w, slab bit b == qubit b+4 (WG w = qubits 0..3).
// RX_s{10..13}, ZZ_{s+1}, RX_{s+1}{4..13}. If REDUCE: also the q=10..13
// expectations (valid: remaining RX_{s+1}{0..3} commutes with them).
template <bool REDUCE>
__device__ void phaseB(Smem& sm, float2* psi, int w, int t,
                       const float* c, const float* s, float* consts) {
    float2 r[4];
#pragma unroll
    for (int j = 0; j < 4; ++j) r[j] = cload2(&psi[(((t << 2) | j) << 4) | w]);
#pragma unroll
    for (int j = 0; j < 4; ++j) bfly_shfl(r[j], 16, c[10], s[10]);
#pragma unroll
    for (int j = 0; j < 4; ++j) bfly_shfl(r[j], 32, c[11], s[11]);
    stage_12(sm.slab, r, t);       // reg bits now = qubits 12,13
    bfly(r[0], r[1], c[12], s[12]); bfly(r[2], r[3], c[12], s[12]);
    bfly(r[0], r[2], c[13], s[13]); bfly(r[1], r[3], c[13], s[13]);
#pragma unroll
    for (int j = 0; j < 4; ++j) zz_apply(sm, r[j], ((t | (j << 8)) << 4) | w);
    bfly(r[0], r[1], c[12], s[12]); bfly(r[2], r[3], c[12], s[12]);
    bfly(r[0], r[2], c[13], s[13]); bfly(r[1], r[3], c[13], s[13]);
#pragma unroll
    for (int b = 0; b < 6; ++b) {
#pragma unroll
        for (int j = 0; j < 4; ++j) bfly_shfl(r[j], 1 << b, c[4 + b], s[4 + b]);
    }
    stage_21(sm.slab, r, t);       // back to mapping1 (regs = qubits 4,5)
#pragma unroll
    for (int j = 0; j < 4; ++j) bfly_shfl(r[j], 16, c[10], s[10]);
#pragma unroll
    for (int j = 0; j < 4; ++j) bfly_shfl(r[j], 32, c[11], s[11]);
#pragma unroll
    for (int j = 0; j < 4; ++j) cstore2(&psi[(((t << 2) | j) << 4) | w], r[j]);

    if (REDUCE) {
        // slab[(t<<2)|j] was last read by this same thread in stage_21 — safe
#pragma unroll
        for (int j = 0; j < 4; ++j) sm.slab[(t << 2) | j] = r[j];
        __syncthreads();
        // qubit q at slab bit q-4; triple i = 13-q
#pragma unroll
        for (int q = 10; q <= 13; ++q) reduce_qubit(sm, q - 4, 13 - q, t);
        __syncthreads();
        if (t < 12)
            __hip_atomic_fetch_add(&consts[t], sm.red[t],
                                   __ATOMIC_RELAXED, __HIP_MEMORY_SCOPE_AGENT);
    }
}

// Final phase (layout A): leftover RX_10{0..3}, then q=0..9 expectations.
// No psi write-back needed.
__device__ void phaseA_final(Smem& sm, const float2* psi, int w, int t,
                             const float* c, const float* s, float* consts) {
    float2 r[4];
#pragma unroll
    for (int j = 0; j < 4; ++j) r[j] = cload2(&psi[(w << 10) | (t << 2) | j]);
    bfly(r[0], r[1], c[0], s[0]); bfly(r[2], r[3], c[0], s[0]);
    bfly(r[0], r[2], c[1], s[1]); bfly(r[1], r[3], c[1], s[1]);
#pragma unroll
    for (int j = 0; j < 4; ++j) bfly_shfl(r[j], 1, c[2], s[2]);
#pragma unroll
    for (int j = 0; j < 4; ++j) bfly_shfl(r[j], 2, c[3], s[3]);
    __syncthreads();
#pragma unroll
    for (int j = 0; j < 4; ++j) sm.slab[(t << 2) | j] = r[j];
    __syncthreads();
#pragma unroll
    for (int q = 0; q <= 9; ++q) reduce_qubit(sm, q, 13 - q, t);
    __syncthreads();
    if (t < 30)
        __hip_atomic_fetch_add(&consts[12 + t], sm.red[12 + t],
                               __ATOMIC_RELAXED, __HIP_MEMORY_SCOPE_AGENT);
}

extern "C" __global__ void __launch_bounds__(NTHR)
qr_all(const float* __restrict__ x, const float* __restrict__ J,
       const float* __restrict__ g, float* __restrict__ out,
       float2* __restrict__ psi, float* __restrict__ consts,
       int* __restrict__ cnt) {
    __shared__ Smem sm;
    const int w = blockIdx.x;
    const int t = threadIdx.x;
    const float dt = 0.1f;   // EVO_TIME / N_TROTTER

    if (t < 64) {
        float phi = 0.0f;
        for (int i = 0; i < 6; ++i) {
            const float h = 0.5f * J[i] * dt;
            phi += ((t >> i) & 1) ? h : -h;
        }
        float sn, cs; __sincosf(phi, &sn, &cs);
        sm.tabLo[t] = make_float2(cs, sn);
    } else if (t < 192) {
        const int v = t - 64;
        float phi = 0.0f;
        for (int i = 0; i < 7; ++i) {
            const float h = 0.5f * J[6 + i] * dt;
            phi += ((v >> i) & 1) ? h : -h;
        }
        float sn, cs; __sincosf(phi, &sn, &cs);
        sm.tabHi[v] = make_float2(cs, sn);
    }
    if (t < 48) sm.red[t] = 0.0f;
    float cc[NQ], ss[NQ];
#pragma unroll
    for (int i = 0; i < NQ; ++i) __sincosf(0.5f * g[i] * dt, &ss[i], &cc[i]);
    __syncthreads();

    int bar = 0;
    // Phase 1 (A): init + ZZ_1 + RX_1{0..9}
    phaseA<true>(sm, psi, w, t, cc, ss);
    gbar(cnt, NWG * ++bar);
    // Phases 2..10
    for (int sstep = 1; sstep <= 9; ++sstep) {
        if (sstep & 1) {
            if (sstep == 9) phaseB<true >(sm, psi, w, t, cc, ss, consts);
            else            phaseB<false>(sm, psi, w, t, cc, ss, consts);
        } else {
            phaseA<false>(sm, psi, w, t, cc, ss);
        }
        gbar(cnt, NWG * ++bar);
    }
    // Phase 11 (A): leftover RX_10{0..3} + reductions q0..9
    phaseA_final(sm, psi, w, t, cc, ss, consts);
    gbar(cnt, NWG * ++bar);

    // Epilogue: cache consts in LDS (coherent loads), then batched outputs
    if (t < 42) sm.red[t] = cloadf(&consts[t]);
    __syncthreads();
    const int gtid = w * NTHR + t;
    for (int task = gtid; task < 2048 * NQ; task += NWG * NTHR) {
        const int b = task / NQ;
        const int i = task - b * NQ;
        const int q = 13 - i;
        const float xv = x[b * NQ + q];
        const float cr = sm.red[3 * i + 0];
        const float ci = sm.red[3 * i + 1];
        const float zz = sm.red[3 * i + 2];
        float sn, cs; __sincosf(xv, &sn, &cs);
        float* o = out + b * (3 * NQ) + 3 * i;
        o[0] = 2.0f * (cs * cr - sn * ci);
        o[1] = 2.0f * (sn * cr + cs * ci);
        o[2] = zz;
    }
}

extern "C" void kernel_launch(void* const* d_in, const int* in_sizes, int n_in,
                              void* d_out, int out_size, void* d_ws, size_t ws_size,
                              hipStream_t stream) {
    const float* x = (const float*)d_in[0];
    const float* J = (const float*)d_in[1];
    const float* g = (const float*)d_in[2];
    float* out    = (float*)d_out;
    float2* psi   = (float2*)d_ws;                                  // 128 KiB
    float* consts = (float*)((char*)d_ws + DIMQ * sizeof(float2));  // 42 floats
    int*   cnt    = (int*)((char*)d_ws + DIMQ * sizeof(float2) + 192);
    (void)in_sizes; (void)n_in; (void)out_size; (void)ws_size;

    // zero consts + barrier counter (d_ws is re-poisoned before every launch)
    hipMemsetAsync((char*)d_ws + DIMQ * sizeof(float2), 0, 256, stream);
    hipLaunchKernelGGL(qr_all, dim3(NWG), dim3(NTHR), 0, stream,
                       x, J, g, out, psi, consts, cnt);
}